// Round 6
// baseline (435.967 us; speedup 1.0000x reference)
//
#include <hip/hip_runtime.h>

// out = min_co( conv2d(x, W, SAME) ) * 2
// x (32,64,128,128) fp32, W (128,64,3,3) fp32 -> out (32,1,128,128) fp32
//
// Round 10: persistent strip blocks + rolling 6-row LDS ring + async stage.
//   R5-R9 lesson: every small-tile variant pays a serial stage->barrier->
//   GEMM cost; pipes sum instead of overlapping (R9: 408k cyc/CU vs 337k
//   of pipe work). Fix the schedule, not the wave split:
//   * grid 256 = 32 b x 8 strips(16 rows); 1 block/CU, 512 thr, 8 waves.
//     launch_bounds(512,2) -> 256 VGPR/wave: R7/R8's register wall gone.
//   * 6-row ring (99.8 KB): tile t (2 out rows) reads slots {2t..2t+3}%6,
//     stages 2 NEW rows into {2t+4,2t+5}%6 (disjoint -> no pre-barrier).
//     Rolling reuse halves staging vs R9 (2 rows per 2 out rows).
//   * T14 async stage: next tile's 8 global loads issue BEFORE the K-loop
//     (HBM ~700cyc hides under ~2300cyc MFMA); cvt+ds_write after the
//     epilogue barrier; barrier B publishes for tile t+1.
//   * K-loop: wm2 x ms2 x wn2 (dup_A=2), 16 MFMA/iter cover, 2-deep B
//     prefetch + 1-deep A ds_read pipeline (regs ~210 of 256).
//   * keep: conflict-free staging remap, v_cvt_pk_bf16_f32, wt[tap][co][ci],
//     s_setprio, DPP row_ror epilogue.

typedef __attribute__((ext_vector_type(8)))  short short8;   // 8 x bf16
typedef __attribute__((ext_vector_type(4)))  float float4v;

#define CI 64
#define CO 128
#define HH 128
#define WW 128
#define WP 130
#define RING 6

#define WT_BYTES ((size_t)9 * CO * CI * 2)   // 147,456

__device__ __forceinline__ unsigned short f2bf(float f) {
    unsigned int u = __float_as_uint(f);
    u = (u + 0x7fffu + ((u >> 16) & 1u)) >> 16;   // RNE
    return (unsigned short)u;
}

template <int CTRL>
__device__ __forceinline__ float fminror(float v) {
    int t = __builtin_amdgcn_mov_dpp(__float_as_int(v), CTRL, 0xF, 0xF, false);
    return fminf(v, __int_as_float(t));
}

// ---- prep_w: W (co,ci,3,3) fp32 -> wt[tap][co][ci] bf16 -------------------

__global__ __launch_bounds__(256) void prep_w(
    const float* __restrict__ Wsrc, unsigned short* __restrict__ wt)
{
    int idx = blockIdx.x * 256 + threadIdx.x;          // (tap, co, ci)
    if (idx >= 9 * CO * CI) return;
    int ci  = idx & 63;
    int t   = idx >> 6;
    int co  = t & 127;
    int tap = t >> 7;
    wt[((size_t)tap * CO + co) * CI + ci] =
        f2bf(Wsrc[((size_t)co * CI + ci) * 9 + tap]);
}

// ---- fused conv + min -----------------------------------------------------

__global__ __launch_bounds__(512, 2) void conv_fused(
    const float* __restrict__ x,
    const unsigned short* __restrict__ wt,
    float* __restrict__ out)
{
    __shared__ __align__(16) char  ldsA[RING * WP * 128];   // 99,840
    __shared__ float scratch[2][2][128];

    const int gid   = blockIdx.x;          // 0..255
    const int strip = gid & 7;
    const int b     = gid >> 3;
    const int base  = strip * 16;          // first output row of strip

    const int tid  = threadIdx.x;
    const int wid  = tid >> 6;
    const int lane = tid & 63;
    const int l15  = lane & 15;
    const int quad = lane >> 4;
    const int hi   = lane >> 5;
    const int wm   = wid & 1;              // output row of the pair
    const int ms   = (wid >> 1) & 1;       // pixel col half
    const int wn   = wid >> 2;             // co half
    const int n0   = wn * 64;
    const int cb   = ms * 64;

    // staging lane mapping (R6-verified conflict-free: 16 banks, 2-way free)
    const int sm  = wid & 3;
    const int sn  = wid >> 2;
    const int cpl = (lane >> 2) & 7;
    const int qlo = (lane & 3) + 4 * hi;   // 0..7
    const int ci0 = 2 * (cpl + 8 * sm);    // 0..62

    // ---- zero pad columns (wp = 0, 129) of all 6 ring rows ----
    if (tid < 96) {
        int r    = tid >> 4;               // 0..5
        int wp   = ((tid >> 3) & 1) ? 129 : 0;
        int s8   = tid & 7;
        float4v z = {0.f, 0.f, 0.f, 0.f};
        *(float4v*)(ldsA + (size_t)(r * WP + wp) * 128 + s8 * 16) = z;
    }

    // ---- prologue: stage local rows 0..3 (x rows base-1..base+2) ----
    #pragma unroll
    for (int k = 0; k < 8; ++k) {
        const int r = k >> 1;                          // ring slot 0..3
        const int h = base - 1 + r;
        const int Q = qlo + 8 * (sn + 2 * (k & 1));    // 0..31
        float4v a0 = {0.f, 0.f, 0.f, 0.f}, a1 = {0.f, 0.f, 0.f, 0.f};
        if (h >= 0) {                                  // h < HH always here
            const float* p0 = x + (((size_t)b * CI + ci0) * HH + h) * WW + Q * 4;
            a0 = *(const float4v*)p0;
            a1 = *(const float4v*)(p0 + (size_t)HH * WW);
        }
        #pragma unroll
        for (int e = 0; e < 4; ++e) {
            const int wp = Q * 4 + e + 1;              // 1..128
            const int sl = (ci0 >> 3) ^ (wp & 7);      // 16B-slot swizzle
            unsigned int pack = 0;
            if (h >= 0)
                asm("v_cvt_pk_bf16_f32 %0, %1, %2"
                    : "=v"(pack) : "v"(a0[e]), "v"(a1[e]));
            *(unsigned int*)(ldsA + (size_t)(r * WP + wp) * 128
                             + sl * 16 + (ci0 & 7) * 2) = pack;
        }
    }

    // ---- per-lane constant addresses ----
    int coladdr[6];
    #pragma unroll
    for (int dw = 0; dw < 3; ++dw) {
        const int key = (dw + l15) & 7;
        #pragma unroll
        for (int kc = 0; kc < 2; ++kc)
            coladdr[dw * 2 + kc] = (dw + cb + l15) * 128
                                 + (((kc * 4 + quad) ^ key) << 4);
    }
    const unsigned short* wl = wt + (n0 + l15) * CI + quad * 8;

    __syncthreads();

    // ---- tile loop: 8 tiles of 2 output rows ----
    #pragma unroll 1
    for (int t = 0; t < 8; ++t) {
        // B pipeline fill (steps 0,1)
        short8 b0[4], b1[4], b2[4];
        #pragma unroll
        for (int nt = 0; nt < 4; ++nt) {
            b0[nt] = *(const short8*)(wl + nt * 16 * CI);
            b1[nt] = *(const short8*)(wl + nt * 16 * CI + 32);
        }
        // async stage loads for tile t+1 (front-loaded; land during K-loop)
        float4v sa[4], sb[4];
        if (t < 7) {
            #pragma unroll
            for (int j = 0; j < 4; ++j) {
                const int rl = j >> 1;
                const int h  = base + 2 * t + 3 + rl;
                if (h < HH) {                          // uniform guard
                    const int Q = qlo + 8 * (sn + 2 * (j & 1));
                    const float* p0 = x + (((size_t)b * CI + ci0) * HH + h) * WW + Q * 4;
                    sa[j] = *(const float4v*)p0;
                    sb[j] = *(const float4v*)(p0 + (size_t)HH * WW);
                }
            }
        }
        // ring row bases for this tile
        const char* ab[3];
        #pragma unroll
        for (int dh = 0; dh < 3; ++dh)
            ab[dh] = ldsA + (size_t)(((2 * t + wm + dh) % RING) * WP) * 128;

        float4v acc[4][4];
        #pragma unroll
        for (int mt = 0; mt < 4; ++mt)
            #pragma unroll
            for (int nt = 0; nt < 4; ++nt)
                acc[mt][nt] = (float4v){0.f, 0.f, 0.f, 0.f};

        // A pipeline fill (step 0: tap0 -> dh0, dw0, kc0)
        short8 af0[4], af1[4];
        #pragma unroll
        for (int mt = 0; mt < 4; ++mt)
            af0[mt] = *(const short8*)(ab[0] + coladdr[0] + mt * 2048);

        #pragma unroll
        for (int it = 0; it < 18; ++it) {
            if (it < 16) {                     // B prefetch, 2 steps ahead
                const int s   = it + 2;
                const int off = (s >> 1) * CO * CI + (s & 1) * 32;
                #pragma unroll
                for (int nt = 0; nt < 4; ++nt)
                    b2[nt] = *(const short8*)(wl + off + nt * 16 * CI);
            }
            if (it < 17) {                     // A ds_read, 1 step ahead
                const int s    = it + 1;
                const int tapn = s >> 1;
                const int dhn  = tapn / 3, dwn = tapn % 3, kcn = s & 1;
                #pragma unroll
                for (int mt = 0; mt < 4; ++mt)
                    af1[mt] = *(const short8*)(ab[dhn]
                               + coladdr[dwn * 2 + kcn] + mt * 2048);
            }
            __builtin_amdgcn_s_setprio(1);
            #pragma unroll
            for (int mt = 0; mt < 4; ++mt)
                #pragma unroll
                for (int nt = 0; nt < 4; ++nt)
                    acc[mt][nt] = __builtin_amdgcn_mfma_f32_16x16x32_bf16(
                        af0[mt], b0[nt], acc[mt][nt], 0, 0, 0);
            __builtin_amdgcn_s_setprio(0);
            #pragma unroll
            for (int mt = 0; mt < 4; ++mt) af0[mt] = af1[mt];
            #pragma unroll
            for (int nt = 0; nt < 4; ++nt) { b0[nt] = b1[nt]; b1[nt] = b2[nt]; }
        }

        // ---- epilogue: min over co ----
        // D: co = n0 + nt*16 + l15, pixel col = cb + mt*16 + quad*4 + reg.
        float pm[4][4];
        #pragma unroll
        for (int mt = 0; mt < 4; ++mt)
            #pragma unroll
            for (int reg = 0; reg < 4; ++reg)
                pm[mt][reg] = fminf(fminf(acc[mt][0][reg], acc[mt][1][reg]),
                                    fminf(acc[mt][2][reg], acc[mt][3][reg]));
        #pragma unroll
        for (int mt = 0; mt < 4; ++mt)
            #pragma unroll
            for (int reg = 0; reg < 4; ++reg) {
                pm[mt][reg] = fminror<0x128>(pm[mt][reg]);   // row_ror:8
                pm[mt][reg] = fminror<0x124>(pm[mt][reg]);   // row_ror:4
                pm[mt][reg] = fminror<0x122>(pm[mt][reg]);   // row_ror:2
                pm[mt][reg] = fminror<0x121>(pm[mt][reg]);   // row_ror:1
            }
        if (l15 == 0) {
            #pragma unroll
            for (int mt = 0; mt < 4; ++mt)
                #pragma unroll
                for (int reg = 0; reg < 4; ++reg)
                    scratch[wn][wm][cb + mt * 16 + quad * 4 + reg] = pm[mt][reg];
        }
        __syncthreads();                       // barrier A: scratch + ring-t done
        if (tid < 256) {
            int r = tid >> 7, c = tid & 127;
            float v = fminf(scratch[0][r][c], scratch[1][r][c]) * 2.0f;
            out[((size_t)b * HH + base + 2 * t + r) * WW + c] = v;
        }
        // ---- publish staged rows into ring slots {2t+4, 2t+5} % 6 ----
        if (t < 7) {
            #pragma unroll
            for (int j = 0; j < 4; ++j) {
                const int rl   = j >> 1;
                const int h    = base + 2 * t + 3 + rl;
                const int slot = (2 * t + 4 + rl) % RING;
                const int Q    = qlo + 8 * (sn + 2 * (j & 1));
                #pragma unroll
                for (int e = 0; e < 4; ++e) {
                    const int wp = Q * 4 + e + 1;
                    const int sl = (ci0 >> 3) ^ (wp & 7);
                    unsigned int pack = 0;
                    if (h < HH)
                        asm("v_cvt_pk_bf16_f32 %0, %1, %2"
                            : "=v"(pack) : "v"(sa[j][e]), "v"(sb[j][e]));
                    *(unsigned int*)(ldsA + (size_t)(slot * WP + wp) * 128
                                     + sl * 16 + (ci0 & 7) * 2) = pack;
                }
            }
        }
        __syncthreads();                       // barrier B: ring t+1 visible
    }
}

// ---------------- fallback (round-1 direct conv) ----------------

#define COT 16
__global__ __launch_bounds__(256) void conv_min_fallback(
    const float* __restrict__ x, const float* __restrict__ Wt,
    float* __restrict__ out)
{
    const int b  = blockIdx.y;
    const int h  = blockIdx.x * 2 + (threadIdx.x >> 7);
    const int w  = threadIdx.x & 127;
    const bool r0 = h > 0, r2 = h < HH - 1, c0 = w > 0, c2 = w < WW - 1;
    const float* xb = x + (size_t)b * CI * HH * WW;
    float vmin = 3.4e38f;
    for (int cb = 0; cb < CO; cb += COT) {
        float acc[COT];
        #pragma unroll
        for (int u = 0; u < COT; ++u) acc[u] = 0.0f;
        #pragma unroll 1
        for (int ci = 0; ci < CI; ++ci) {
            const float* xp = xb + ((size_t)ci * HH + h) * WW + w;
            float xv[9];
            xv[0] = (r0 && c0) ? xp[-WW - 1] : 0.0f;
            xv[1] =  r0        ? xp[-WW    ] : 0.0f;
            xv[2] = (r0 && c2) ? xp[-WW + 1] : 0.0f;
            xv[3] =        c0  ? xp[-1     ] : 0.0f;
            xv[4] =              xp[0      ];
            xv[5] =        c2  ? xp[1      ] : 0.0f;
            xv[6] = (r2 && c0) ? xp[ WW - 1] : 0.0f;
            xv[7] =  r2        ? xp[ WW    ] : 0.0f;
            xv[8] = (r2 && c2) ? xp[ WW + 1] : 0.0f;
            #pragma unroll
            for (int u = 0; u < COT; ++u) {
                const float* wp = Wt + ((size_t)(cb + u) * CI + ci) * 9;
                acc[u] += wp[0]*xv[0] + wp[1]*xv[1] + wp[2]*xv[2]
                        + wp[3]*xv[3] + wp[4]*xv[4] + wp[5]*xv[5]
                        + wp[6]*xv[6] + wp[7]*xv[7] + wp[8]*xv[8];
            }
        }
        #pragma unroll
        for (int u = 0; u < COT; ++u) vmin = fminf(vmin, acc[u]);
    }
    out[((size_t)b * HH + h) * WW + w] = vmin * 2.0f;
}

// ---------------- launch ----------------

extern "C" void kernel_launch(void* const* d_in, const int* in_sizes, int n_in,
                              void* d_out, int out_size, void* d_ws, size_t ws_size,
                              hipStream_t stream) {
    const float* x  = (const float*)d_in[0];   // (32,64,128,128)
    const float* Ws = (const float*)d_in[1];   // (128,64,3,3)
    float* out = (float*)d_out;                // (32,1,128,128)

    if (ws_size < WT_BYTES) {
        dim3 grid(HH / 2, 32);
        conv_min_fallback<<<grid, 256, 0, stream>>>(x, Ws, out);
        return;
    }

    unsigned short* wt = (unsigned short*)d_ws;

    prep_w<<<(9 * CO * CI + 255) / 256, 256, 0, stream>>>(Ws, wt);
    conv_fused<<<256, 512, 0, stream>>>(x, wt, out);
}

// Round 7
// 261.106 us; speedup vs baseline: 1.6697x; 1.6697x over previous
//
#include <hip/hip_runtime.h>

// out = min_co( conv2d(x, W, SAME) ) * 2
// x (32,64,128,128) fp32, W (128,64,3,3) fp32 -> out (32,1,128,128) fp32
//
// Round 11: R6 geometry (best verified, 124 us) + dup_A=2 wave split with
// a MINIMAL-register K-loop. R10's lesson: never hand-roll multi-deep
// buffers across an unrolled MFMA loop (212 MB spill); keep the live set
// small and let the compiler pipeline straight-line code.
//   * waves 2x2x2 (wm row, ms col-half, wn co-half): 4mt x 4nt frags,
//     A ds_read_b128 halved vs R6 (576/block), 16-MFMA cover kept.
//   * B single-buffered; wt2[tap][kc][co][32] layout -> per step the 4
//     nt loads are +0/1024/2048/3072 B (imm13): 1 v_add + 4 loads/iter.
//     B is L1-resident (8 KB/step shared by 16 waves).
//   * K-loop arch live set ~56 regs (<=64 at launch_bounds(512,4));
//     acc[4][4] = 64 AGPR. No spill.
//   * verbatim-verified pieces: R6 staging remap (conflict-free),
//     v_cvt_pk_bf16_f32, R8 aaddr scheme (max ds imm 39424 < 64K),
//     DPP row_ror epilogue, s_setprio, 2-slice scratch.

typedef __attribute__((ext_vector_type(8)))  short short8;   // 8 x bf16
typedef __attribute__((ext_vector_type(4)))  float float4v;

#define CI 64
#define CO 128
#define HH 128
#define WW 128
#define WP 130

#define WT_BYTES ((size_t)9 * CO * CI * 2)   // 147,456

__device__ __forceinline__ unsigned short f2bf(float f) {
    unsigned int u = __float_as_uint(f);
    u = (u + 0x7fffu + ((u >> 16) & 1u)) >> 16;   // RNE
    return (unsigned short)u;
}

template <int CTRL>
__device__ __forceinline__ float fminror(float v) {
    int t = __builtin_amdgcn_mov_dpp(__float_as_int(v), CTRL, 0xF, 0xF, false);
    return fminf(v, __int_as_float(t));
}

// ---- prep_w: W (co,ci,3,3) fp32 -> wt2[tap][kc][co][cik] bf16 -------------
// (tap, kc = ci>>5, co, cik = ci&31): the K-loop's 4 nt-loads per step are
// contiguous-strided by 1024 B (imm13-foldable).

__global__ __launch_bounds__(256) void prep_w(
    const float* __restrict__ Wsrc, unsigned short* __restrict__ wt)
{
    int idx = blockIdx.x * 256 + threadIdx.x;          // (tap, co, ci)
    if (idx >= 9 * CO * CI) return;
    int ci  = idx & 63;
    int t   = idx >> 6;
    int co  = t & 127;
    int tap = t >> 7;
    int kc  = ci >> 5;
    int cik = ci & 31;
    wt[(((size_t)tap * 2 + kc) * CO + co) * 32 + cik] =
        f2bf(Wsrc[((size_t)co * CI + ci) * 9 + tap]);
}

// ---- fused conv + min -----------------------------------------------------

#define LDSA_BYTES (4 * WP * CI * 2)   // 66,560 : 4 padded rows, 128 B/pixel

__global__ __launch_bounds__(512, 4) void conv_fused(
    const float* __restrict__ x,
    const unsigned short* __restrict__ wt,
    float* __restrict__ out)
{
    __shared__ __align__(16) char  ldsA[LDSA_BYTES];
    __shared__ float scratch[2][2][128];

    const int bx   = blockIdx.x;       // output rows 2bx, 2bx+1
    const int b    = blockIdx.y;
    const int tid  = threadIdx.x;
    const int wid  = tid >> 6;
    const int lane = tid & 63;
    const int l15  = lane & 15;
    const int quad = lane >> 4;
    const int hi   = lane >> 5;
    const int wm   = wid & 1;          // output row of the pair
    const int ms   = (wid >> 1) & 1;   // pixel col half (64 cols)
    const int wn   = wid >> 2;         // co half (64 co)
    const int n0   = wn * 64;
    const int cb   = ms * 64;          // pixel column base

    // ---- zero pad columns (wp = 0, 129) of all 4 LDS rows ----
    if (tid < 64) {
        int r    = tid >> 4;
        int wp   = ((tid >> 3) & 1) ? 129 : 0;
        int slot = tid & 7;
        float4v z = {0.f, 0.f, 0.f, 0.f};
        *(float4v*)(ldsA + ((size_t)(r * WP + wp) * 128) + slot * 16) = z;
    }
    // ---- zero out-of-bounds rows (edge blocks only; uniform branch) ----
    if (bx == 0) {                      // LDS row 0 = x row -1
        float4v z = {0.f, 0.f, 0.f, 0.f};
        for (int i = tid; i < WP * CI * 2 / 16; i += 512)
            ((float4v*)ldsA)[i] = z;
    }
    if (bx == HH / 2 - 1) {             // LDS row 3 = x row 128
        float4v z = {0.f, 0.f, 0.f, 0.f};
        for (int i = tid; i < WP * CI * 2 / 16; i += 512)
            ((float4v*)(ldsA + 3 * WP * 128))[i] = z;
    }

    // ---- stage: fp32 -> bf16 transpose into LDS (conflict-free writes) ----
    // R6-verified lane remap: ci varies in lane bits 2-4, w-quad in bits
    // 0-1,5 -> each 32-lane phase hits 16 distinct banks (2-way = free).
    {
        const int sm  = wid & 3;                      // staging role
        const int sn  = wid >> 2;
        const int cpl = (lane >> 2) & 7;
        const int qlo = (lane & 3) + 4 * hi;          // 0..7
        const int ci0 = 2 * (cpl + 8 * sm);           // 0..62
        #pragma unroll
        for (int k = 0; k < 8; ++k) {
            const int r = k >> 1;
            const int Q = qlo + 8 * (sn + 2 * (k & 1));   // 0..31
            const int h = 2 * bx - 1 + r;
            if (h >= 0 && h < HH) {
                const float* p0 = x + (((size_t)b * CI + ci0) * HH + h) * WW + Q * 4;
                float4v a0 = *(const float4v*)p0;
                float4v a1 = *(const float4v*)(p0 + (size_t)HH * WW);
                #pragma unroll
                for (int e = 0; e < 4; ++e) {
                    const int wp   = Q * 4 + e + 1;           // 1..128
                    const int slot = (ci0 >> 3) ^ (wp & 7);   // 16B-slot swizzle
                    unsigned int pack;                        // lo=ci0, hi=ci0+1
                    asm("v_cvt_pk_bf16_f32 %0, %1, %2"
                        : "=v"(pack) : "v"(a0[e]), "v"(a1[e]));
                    *(unsigned int*)(ldsA + (size_t)(r * WP + wp) * 128
                                     + slot * 16 + (ci0 & 7) * 2) = pack;
                }
            }
        }
    }
    __syncthreads();

    // ---- K-loop: 9 taps x 2 kc, 16 MFMAs (4mt x 4nt) per step ----
    // A addr: 6 bases (dw,kc); dh,mt are ds_read imms (max 39424 < 64K).
    int aaddr[6];
    #pragma unroll
    for (int dw = 0; dw < 3; ++dw) {
        const int key = (dw + l15) & 7;
        #pragma unroll
        for (int kc = 0; kc < 2; ++kc)
            aaddr[dw * 2 + kc] = (wm * WP + dw + cb + l15) * 128
                               + (((kc * 4 + quad) ^ key) << 4);
    }
    // B: per-lane base; per step one uniform advance, 4 loads at +nt*1024 B.
    const unsigned short* wl = wt + (n0 + l15) * 32 + quad * 8;

    float4v acc[4][4];
    #pragma unroll
    for (int mt = 0; mt < 4; ++mt)
        #pragma unroll
        for (int nt = 0; nt < 4; ++nt)
            acc[mt][nt] = (float4v){0.f, 0.f, 0.f, 0.f};

    #pragma unroll
    for (int it = 0; it < 18; ++it) {
        const int tap = it >> 1;
        const int kc  = it & 1;
        const int dh  = tap / 3;
        const int dw  = tap % 3;

        const unsigned short* bp = wl + (size_t)it * (CO * 32);
        short8 bf[4];
        #pragma unroll
        for (int nt = 0; nt < 4; ++nt)
            bf[nt] = *(const short8*)(bp + nt * 16 * 32);

        const char* ab = ldsA + aaddr[dw * 2 + kc];   // static index
        short8 af[4];
        #pragma unroll
        for (int mt = 0; mt < 4; ++mt)
            af[mt] = *(const short8*)(ab + dh * (WP * 128) + mt * 2048);

        __builtin_amdgcn_s_setprio(1);
        #pragma unroll
        for (int mt = 0; mt < 4; ++mt)
            #pragma unroll
            for (int nt = 0; nt < 4; ++nt)
                acc[mt][nt] = __builtin_amdgcn_mfma_f32_16x16x32_bf16(
                    af[mt], bf[nt], acc[mt][nt], 0, 0, 0);
        __builtin_amdgcn_s_setprio(0);
    }

    // ---- epilogue: min over co, *2 ----
    // D: co = n0 + nt*16 + l15, pixel col = cb + mt*16 + quad*4 + reg.
    float pm[4][4];
    #pragma unroll
    for (int mt = 0; mt < 4; ++mt)
        #pragma unroll
        for (int reg = 0; reg < 4; ++reg)
            pm[mt][reg] = fminf(fminf(acc[mt][0][reg], acc[mt][1][reg]),
                                fminf(acc[mt][2][reg], acc[mt][3][reg]));
    #pragma unroll
    for (int mt = 0; mt < 4; ++mt)
        #pragma unroll
        for (int reg = 0; reg < 4; ++reg) {
            pm[mt][reg] = fminror<0x128>(pm[mt][reg]);   // row_ror:8
            pm[mt][reg] = fminror<0x124>(pm[mt][reg]);   // row_ror:4
            pm[mt][reg] = fminror<0x122>(pm[mt][reg]);   // row_ror:2
            pm[mt][reg] = fminror<0x121>(pm[mt][reg]);   // row_ror:1
        }
    if (l15 == 0) {
        #pragma unroll
        for (int mt = 0; mt < 4; ++mt)
            #pragma unroll
            for (int reg = 0; reg < 4; ++reg)
                scratch[wn][wm][cb + mt * 16 + quad * 4 + reg] = pm[mt][reg];
    }
    __syncthreads();
    if (tid < 256) {
        int r = tid >> 7, c = tid & 127;
        float v = fminf(scratch[0][r][c], scratch[1][r][c]) * 2.0f;
        out[((size_t)b * HH + 2 * bx + r) * WW + c] = v;
    }
}

// ---------------- fallback (round-1 direct conv) ----------------

#define COT 16
__global__ __launch_bounds__(256) void conv_min_fallback(
    const float* __restrict__ x, const float* __restrict__ Wt,
    float* __restrict__ out)
{
    const int b  = blockIdx.y;
    const int h  = blockIdx.x * 2 + (threadIdx.x >> 7);
    const int w  = threadIdx.x & 127;
    const bool r0 = h > 0, r2 = h < HH - 1, c0 = w > 0, c2 = w < WW - 1;
    const float* xb = x + (size_t)b * CI * HH * WW;
    float vmin = 3.4e38f;
    for (int cb = 0; cb < CO; cb += COT) {
        float acc[COT];
        #pragma unroll
        for (int u = 0; u < COT; ++u) acc[u] = 0.0f;
        #pragma unroll 1
        for (int ci = 0; ci < CI; ++ci) {
            const float* xp = xb + ((size_t)ci * HH + h) * WW + w;
            float xv[9];
            xv[0] = (r0 && c0) ? xp[-WW - 1] : 0.0f;
            xv[1] =  r0        ? xp[-WW    ] : 0.0f;
            xv[2] = (r0 && c2) ? xp[-WW + 1] : 0.0f;
            xv[3] =        c0  ? xp[-1     ] : 0.0f;
            xv[4] =              xp[0      ];
            xv[5] =        c2  ? xp[1      ] : 0.0f;
            xv[6] = (r2 && c0) ? xp[ WW - 1] : 0.0f;
            xv[7] =  r2        ? xp[ WW    ] : 0.0f;
            xv[8] = (r2 && c2) ? xp[ WW + 1] : 0.0f;
            #pragma unroll
            for (int u = 0; u < COT; ++u) {
                const float* wp = Wt + ((size_t)(cb + u) * CI + ci) * 9;
                acc[u] += wp[0]*xv[0] + wp[1]*xv[1] + wp[2]*xv[2]
                        + wp[3]*xv[3] + wp[4]*xv[4] + wp[5]*xv[5]
                        + wp[6]*xv[6] + wp[7]*xv[7] + wp[8]*xv[8];
            }
        }
        #pragma unroll
        for (int u = 0; u < COT; ++u) vmin = fminf(vmin, acc[u]);
    }
    out[((size_t)b * HH + h) * WW + w] = vmin * 2.0f;
}

// ---------------- launch ----------------

extern "C" void kernel_launch(void* const* d_in, const int* in_sizes, int n_in,
                              void* d_out, int out_size, void* d_ws, size_t ws_size,
                              hipStream_t stream) {
    const float* x  = (const float*)d_in[0];   // (32,64,128,128)
    const float* Ws = (const float*)d_in[1];   // (128,64,3,3)
    float* out = (float*)d_out;                // (32,1,128,128)

    if (ws_size < WT_BYTES) {
        dim3 grid(HH / 2, 32);
        conv_min_fallback<<<grid, 256, 0, stream>>>(x, Ws, out);
        return;
    }

    unsigned short* wt = (unsigned short*)d_ws;

    prep_w<<<(9 * CO * CI + 255) / 256, 256, 0, stream>>>(Ws, wt);
    conv_fused<<<dim3(HH / 2, 32), 512, 0, stream>>>(x, wt, out);
}